// Round 10
// baseline (358.534 us; speedup 1.0000x reference)
//
#include <hip/hip_runtime.h>
#include <hip/hip_bf16.h>
#include <hip/hip_fp16.h>
#include <math.h>

#define N_NODES 50000
#define E_EDGES 800000
#define NEG_SLOPE 0.2f
#define EPS 1e-16f
#define NB_SCAN ((N_NODES + 255) / 256)   // 196

typedef _Float16 f16x8 __attribute__((ext_vector_type(8)));
typedef float    f32x4 __attribute__((ext_vector_type(4)));

__device__ __forceinline__ float leaky(float v) {
    return v > 0.f ? v : NEG_SLOPE * v;
}

// load 8 contiguous elements as f16x8, converting if input is fp32
__device__ __forceinline__ f16x8 load8(const float* p) {
    const float4 v0 = *(const float4*)p;
    const float4 v1 = *(const float4*)(p + 4);
    f16x8 r;
    r[0] = (_Float16)v0.x; r[1] = (_Float16)v0.y;
    r[2] = (_Float16)v0.z; r[3] = (_Float16)v0.w;
    r[4] = (_Float16)v1.x; r[5] = (_Float16)v1.y;
    r[6] = (_Float16)v1.z; r[7] = (_Float16)v1.w;
    return r;
}
__device__ __forceinline__ f16x8 load8(const _Float16* p) {
    return *(const f16x8*)p;
}

// ---------------------------------------------------------------------------
// MFMA GEMM (fp16 compute, fp32 accum): Y[N, M2] = X[N,K] @ Wt[M2,K]^T,
// fp16 output. X fp32 (converted during staging) or fp16, templated.
// 128x256 tile, BK=32, 4 waves (2x2 over 64x128 each), 4x8 MFMA tiles/wave.
// OPERANDS SWAPPED vs conventional: acc = mfma(W-frag, X-frag) so the D tile
// is [feature][node] -> lane holds 4 CONSECUTIVE features of one node per
// tile => epilogue packs them into one uint2 (4 halves) store. 32 vector
// stores/thread instead of 128 scalar stores.
// A/B fragment layouts are operand-symmetric: both read 8 contiguous halves
// at [m or n = lane&15][k = (lane>>4)*8 .. +7] (ds_read_b128).
// ---------------------------------------------------------------------------
template <typename IT>
__global__ __launch_bounds__(256, 2)
void gemm_mfma(const IT* __restrict__ X, const __half* __restrict__ Wth,
               __half* __restrict__ Y, int Nrows, int K, int M2)
{
    const _Float16* Wt = (const _Float16*)Wth;
    __shared__ _Float16 As[128][40];
    __shared__ _Float16 Bs[256][40];
    const int tid  = threadIdx.x;
    const int row0 = blockIdx.x * 128;
    const int col0 = blockIdx.y * 256;
    const int lane = tid & 63;
    const int wv   = tid >> 6;
    const int wr   = (wv >> 1) * 64;     // wave row (node) offset
    const int wc   = (wv & 1) * 128;     // wave col (feature) offset
    const int fm   = lane & 15;
    const int fk   = (lane >> 4) * 8;
    const int quad = lane >> 4;

    f32x4 acc[4][8] = {};

    for (int k0 = 0; k0 < K; k0 += 32) {
        // stage X: 128 rows x 32 halves = 512 x 8-half chunks, 2/thread
        #pragma unroll
        for (int p = 0; p < 2; ++p) {
            const int idx = tid + p * 256;
            const int r = idx >> 2;
            const int c = (idx & 3) * 8;
            const int gr = row0 + r;
            f16x8 v = {};
            if (gr < Nrows)
                v = load8(X + (size_t)gr * K + k0 + c);
            *(f16x8*)&As[r][c] = v;
        }
        // stage Wt: 256 rows x 32 halves = 1024 chunks, 4/thread
        #pragma unroll
        for (int p = 0; p < 4; ++p) {
            const int idx = tid + p * 256;
            const int r = idx >> 2;
            const int c = (idx & 3) * 8;
            *(f16x8*)&Bs[r][c] = *(const f16x8*)(Wt + (size_t)(col0 + r) * K + k0 + c);
        }
        __syncthreads();

        f16x8 bf[8];
        #pragma unroll
        for (int j = 0; j < 8; ++j)
            bf[j] = *(const f16x8*)&Bs[wc + j * 16 + fm][fk];
        #pragma unroll
        for (int i = 0; i < 4; ++i) {
            const f16x8 af = *(const f16x8*)&As[wr + i * 16 + fm][fk];
            #pragma unroll
            for (int j = 0; j < 8; ++j)
                // A-operand = weight frag, B-operand = x frag:
                // D[feature][node]; col(lane&15)=node, row(quad*4+rg)=feature
                acc[i][j] = __builtin_amdgcn_mfma_f32_16x16x32_f16(bf[j], af, acc[i][j], 0, 0, 0);
        }
        __syncthreads();
    }

    // epilogue: per (i,j) tile, lane owns node=row0+wr+i*16+fm and features
    // col0+wc+j*16+quad*4 .. +3 -> one uint2 (4 halves) store.
    #pragma unroll
    for (int i = 0; i < 4; ++i) {
        const int node = row0 + wr + i * 16 + fm;
        if (node < Nrows) {
            #pragma unroll
            for (int j = 0; j < 8; ++j) {
                const int feat = col0 + wc + j * 16 + quad * 4;
                union { uint2 u; __half2 h2[2]; } O;
                O.h2[0] = __floats2half2_rn(acc[i][j][0], acc[i][j][1]);
                O.h2[1] = __floats2half2_rn(acc[i][j][2], acc[i][j][3]);
                *(uint2*)(Y + (size_t)node * M2 + feat) = O.u;
            }
        }
    }
}

// both weight pairs -> fp16 transposed, one launch.
// W1t [512,128] from Wl1/Wr1 (K=128,M=256); W2t [256,256] from Wl2/Wr2.
__global__ __launch_bounds__(256)
void cvt_weights(const float* __restrict__ Wl1, const float* __restrict__ Wr1,
                 const float* __restrict__ Wl2, const float* __restrict__ Wr2,
                 __half* __restrict__ W1t, __half* __restrict__ W2t)
{
    int id = blockIdx.x * 256 + threadIdx.x;
    if (id < 512 * 128) {
        const int n = id >> 7, k = id & 127;          // K=128, M=256
        const float* W = (n < 256) ? Wl1 : Wr1;
        const int nn = (n < 256) ? n : n - 256;
        W1t[id] = __float2half(W[(size_t)k * 256 + nn]);
    } else {
        id -= 512 * 128;
        if (id >= 256 * 256) return;
        const int n = id >> 8, k = id & 255;          // K=256, M=128
        const float* W = (n < 128) ? Wl2 : Wr2;
        const int nn = (n < 128) ? n : n - 128;
        W2t[id] = __float2half(W[(size_t)k * 128 + nn]);
    }
}

// ---------------------------------------------------------------------------
// CSR build: histogram -> two-phase parallel scan -> scatter.
// ---------------------------------------------------------------------------
__global__ __launch_bounds__(256)
void hist_dst(const int* __restrict__ dst, int* __restrict__ deg, int E)
{
    int i = blockIdx.x * blockDim.x + threadIdx.x;
    if (i < E) atomicAdd(&deg[dst[i]], 1);
}

__global__ __launch_bounds__(256)
void scan_local(const int* __restrict__ deg, int* __restrict__ locpre,
                int* __restrict__ blockSum)
{
    const int i = blockIdx.x * 256 + threadIdx.x;
    const int lane = threadIdx.x & 63;
    const int wid = threadIdx.x >> 6;
    const int val = (i < N_NODES) ? deg[i] : 0;

    int v = val;
    #pragma unroll
    for (int off = 1; off < 64; off <<= 1) {
        int t = __shfl_up(v, off, 64);
        if (lane >= off) v += t;
    }
    __shared__ int ws[4];
    if (lane == 63) ws[wid] = v;
    __syncthreads();
    int woff = 0;
    for (int k = 0; k < wid; ++k) woff += ws[k];
    if (i < N_NODES) locpre[i] = woff + v - val;
    if (threadIdx.x == 255) blockSum[blockIdx.x] = woff + v;
}

__global__ __launch_bounds__(256)
void scan_final(const int* __restrict__ locpre, const int* __restrict__ blockSum,
                int* __restrict__ rowptr, int* __restrict__ cursor)
{
    const int b = blockIdx.x;
    const int t = threadIdx.x;
    int v = (t < b) ? blockSum[t] : 0;          // NB_SCAN(=196) < 256
    #pragma unroll
    for (int off = 32; off; off >>= 1) v += __shfl_xor(v, off, 64);
    __shared__ int ws[4];
    if ((t & 63) == 0) ws[t >> 6] = v;
    __syncthreads();
    const int offset = ws[0] + ws[1] + ws[2] + ws[3];

    const int i = b * 256 + t;
    if (i < N_NODES) {
        const int rp = locpre[i] + offset;
        rowptr[i] = rp;
        cursor[i] = rp;
    }
    if (b == 0 && t == 0) rowptr[N_NODES] = E_EDGES;
}

__global__ __launch_bounds__(256)
void scatter_edges(const int* __restrict__ src, const int* __restrict__ dst,
                   int* __restrict__ cursor, int* __restrict__ ssrc, int E)
{
    int i = blockIdx.x * blockDim.x + threadIdx.x;
    if (i < E) {
        int pos = atomicAdd(&cursor[dst[i]], 1);
        ssrc[pos] = src[i];
    }
}

// ---------------------------------------------------------------------------
// Layer-1 aggregation (H=4, C=64) — R7 shape (best measured). One wave per
// dst node; lane owns 4 ch (head = lane>>4). 4-edge unroll, butterflies
// interleaved level-by-level.
// ---------------------------------------------------------------------------
__global__ __launch_bounds__(256)
void agg1(const __half* __restrict__ xlr, const int* __restrict__ rowptr,
          const int* __restrict__ ssrc, const float* __restrict__ att,
          const float* __restrict__ b, __half* __restrict__ h)
{
    const int w = (blockIdx.x * blockDim.x + threadIdx.x) >> 6;
    if (w >= N_NODES) return;
    const int lane = threadIdx.x & 63;
    const int ch = lane * 4;

    const float4 at = *(const float4*)(att + ch);
    const float4 bb = *(const float4*)(b + ch);
    union { uint2 u; __half2 h2[2]; } R;
    R.u = *(const uint2*)(xlr + (size_t)w * 512 + 256 + ch);
    const float2 r01 = __half22float2(R.h2[0]);
    const float2 r23 = __half22float2(R.h2[1]);

    float4 a = make_float4(0.f, 0.f, 0.f, 0.f);
    float den = 0.f;

    const int beg = rowptr[w], end = rowptr[w + 1];
    int i = beg;
    while (i + 4 <= end) {
        uint2 u[4];
        #pragma unroll
        for (int j = 0; j < 4; ++j) {
            const int s = ssrc[i + j];
            u[j] = *(const uint2*)(xlr + (size_t)s * 512 + ch);
        }
        float2 p01[4], p23[4];
        float m[4];
        #pragma unroll
        for (int j = 0; j < 4; ++j) {
            union { uint2 uu; __half2 h2[2]; } U; U.uu = u[j];
            p01[j] = __half22float2(U.h2[0]);
            p23[j] = __half22float2(U.h2[1]);
            m[j] = leaky(p01[j].x + r01.x) * at.x
                 + leaky(p01[j].y + r01.y) * at.y
                 + leaky(p23[j].x + r23.x) * at.z
                 + leaky(p23[j].y + r23.y) * at.w;
        }
        #pragma unroll
        for (int off = 1; off < 16; off <<= 1)
            #pragma unroll
            for (int j = 0; j < 4; ++j)
                m[j] += __shfl_xor(m[j], off, 64);
        #pragma unroll
        for (int j = 0; j < 4; ++j) {
            const float e = __expf(m[j]);
            a.x += e * p01[j].x; a.y += e * p01[j].y;
            a.z += e * p23[j].x; a.w += e * p23[j].y;
            den += e;
        }
        i += 4;
    }
    while (i < end) {
        const int s = ssrc[i];
        union { uint2 uu; __half2 h2[2]; } U;
        U.uu = *(const uint2*)(xlr + (size_t)s * 512 + ch);
        const float2 p01 = __half22float2(U.h2[0]);
        const float2 p23 = __half22float2(U.h2[1]);
        float m = leaky(p01.x + r01.x) * at.x
                + leaky(p01.y + r01.y) * at.y
                + leaky(p23.x + r23.x) * at.z
                + leaky(p23.y + r23.y) * at.w;
        m += __shfl_xor(m, 1, 64);
        m += __shfl_xor(m, 2, 64);
        m += __shfl_xor(m, 4, 64);
        m += __shfl_xor(m, 8, 64);
        const float e = __expf(m);
        a.x += e * p01.x; a.y += e * p01.y;
        a.z += e * p23.x; a.w += e * p23.y;
        den += e;
        ++i;
    }

    const float inv = 1.f / (den + EPS);
    float v0 = a.x * inv + bb.x;
    float v1 = a.y * inv + bb.y;
    float v2 = a.z * inv + bb.z;
    float v3 = a.w * inv + bb.w;
    v0 = v0 > 0.f ? v0 : __expf(v0) - 1.f;
    v1 = v1 > 0.f ? v1 : __expf(v1) - 1.f;
    v2 = v2 > 0.f ? v2 : __expf(v2) - 1.f;
    v3 = v3 > 0.f ? v3 : __expf(v3) - 1.f;
    union { uint2 u; __half2 h2[2]; } O;
    O.h2[0] = __floats2half2_rn(v0, v1);
    O.h2[1] = __floats2half2_rn(v2, v3);
    *(uint2*)(h + (size_t)w * 256 + ch) = O.u;
}

// ---------------------------------------------------------------------------
// Layer-2 aggregation (H=1, C=128) — R7 shape. Two 32-lane halves, 2-edge
// unroll per half (4 gathers in flight).
// ---------------------------------------------------------------------------
__global__ __launch_bounds__(256)
void agg2(const __half* __restrict__ xlr, const int* __restrict__ rowptr,
          const int* __restrict__ ssrc, const float* __restrict__ att,
          const float* __restrict__ b, float* __restrict__ out)
{
    const int w = (blockIdx.x * blockDim.x + threadIdx.x) >> 6;
    if (w >= N_NODES) return;
    const int lane = threadIdx.x & 63;
    const int half = lane >> 5;
    const int ch = (lane & 31) * 4;

    const float4 at = *(const float4*)(att + ch);
    const float4 bb = *(const float4*)(b + ch);
    union { uint2 u; __half2 h2[2]; } R;
    R.u = *(const uint2*)(xlr + (size_t)w * 256 + 128 + ch);
    const float2 r01 = __half22float2(R.h2[0]);
    const float2 r23 = __half22float2(R.h2[1]);

    float4 a = make_float4(0.f, 0.f, 0.f, 0.f);
    float den = 0.f;

    const int beg = rowptr[w], end = rowptr[w + 1];
    int i = beg + half;
    while (i + 2 < end) {
        uint2 u[2];
        #pragma unroll
        for (int j = 0; j < 2; ++j) {
            const int s = ssrc[i + 2 * j];
            u[j] = *(const uint2*)(xlr + (size_t)s * 256 + ch);
        }
        float2 p01[2], p23[2];
        float m[2];
        #pragma unroll
        for (int j = 0; j < 2; ++j) {
            union { uint2 uu; __half2 h2[2]; } U; U.uu = u[j];
            p01[j] = __half22float2(U.h2[0]);
            p23[j] = __half22float2(U.h2[1]);
            m[j] = leaky(p01[j].x + r01.x) * at.x
                 + leaky(p01[j].y + r01.y) * at.y
                 + leaky(p23[j].x + r23.x) * at.z
                 + leaky(p23[j].y + r23.y) * at.w;
        }
        #pragma unroll
        for (int off = 1; off < 32; off <<= 1)
            #pragma unroll
            for (int j = 0; j < 2; ++j)
                m[j] += __shfl_xor(m[j], off, 64);
        #pragma unroll
        for (int j = 0; j < 2; ++j) {
            const float e = __expf(m[j]);
            a.x += e * p01[j].x; a.y += e * p01[j].y;
            a.z += e * p23[j].x; a.w += e * p23[j].y;
            den += e;
        }
        i += 4;
    }
    if (i < end) {
        const int s = ssrc[i];
        union { uint2 uu; __half2 h2[2]; } U;
        U.uu = *(const uint2*)(xlr + (size_t)s * 256 + ch);
        const float2 p01 = __half22float2(U.h2[0]);
        const float2 p23 = __half22float2(U.h2[1]);
        float m = leaky(p01.x + r01.x) * at.x
                + leaky(p01.y + r01.y) * at.y
                + leaky(p23.x + r23.x) * at.z
                + leaky(p23.y + r23.y) * at.w;
        #pragma unroll
        for (int off = 1; off < 32; off <<= 1)
            m += __shfl_xor(m, off, 64);
        const float e = __expf(m);
        a.x += e * p01.x; a.y += e * p01.y;
        a.z += e * p23.x; a.w += e * p23.y;
        den += e;
    }

    a.x += __shfl_xor(a.x, 32, 64);
    a.y += __shfl_xor(a.y, 32, 64);
    a.z += __shfl_xor(a.z, 32, 64);
    a.w += __shfl_xor(a.w, 32, 64);
    den += __shfl_xor(den, 32, 64);

    if (half == 0) {
        const float inv = 1.f / (den + EPS);
        float4 o;
        o.x = a.x * inv + bb.x;
        o.y = a.y * inv + bb.y;
        o.z = a.z * inv + bb.z;
        o.w = a.w * inv + bb.w;
        *(float4*)(out + (size_t)w * 128 + ch) = o;
    }
}

extern "C" void kernel_launch(void* const* d_in, const int* in_sizes, int n_in,
                              void* d_out, int out_size, void* d_ws, size_t ws_size,
                              hipStream_t stream)
{
    const float* x    = (const float*)d_in[0];
    const int*   ei   = (const int*)d_in[1];
    const float* Wl1  = (const float*)d_in[2];
    const float* Wr1  = (const float*)d_in[3];
    const float* att1 = (const float*)d_in[4];
    const float* b1   = (const float*)d_in[5];
    const float* Wl2  = (const float*)d_in[6];
    const float* Wr2  = (const float*)d_in[7];
    const float* att2 = (const float*)d_in[8];
    const float* b2   = (const float*)d_in[9];
    const int* src = ei;
    const int* dst = ei + E_EDGES;
    float* out = (float*)d_out;

    // Workspace layout (fp16 unless noted):
    //   xlr1 [N,512] = [xl1|xr1]   (51.2 MB)
    //   hh   [N,256]               (layer-1 ELU output)
    //   xlr2 [N,256] = [xl2|xr2]   (overlays xlr1 — dead after agg1)
    //   W1t  [512,128], W2t [256,256]
    //   ints: rowptr[N+1], cursor[N], deg[N], ssrc[E], locpre[N], blockSum[NB]
    __half* xlr1 = (__half*)d_ws;
    __half* hh   = xlr1 + (size_t)N_NODES * 512;
    __half* W1t  = hh + (size_t)N_NODES * 256;
    __half* W2t  = W1t + 512 * 128;
    int* rowptr   = (int*)(W2t + 256 * 256);
    int* cursor   = rowptr + (N_NODES + 1);
    int* deg      = cursor + N_NODES;
    int* ssrc     = deg + N_NODES;
    int* locpre   = ssrc + E_EDGES;
    int* blockSum = locpre + N_NODES;
    __half* xlr2 = xlr1;

    const dim3 blk(256);
    const int gemm_gx = (N_NODES + 127) / 128;   // 391

    // --- weight converts (one launch) ---
    cvt_weights<<<(512 * 128 + 256 * 256 + 255) / 256, blk, 0, stream>>>(
        Wl1, Wr1, Wl2, Wr2, W1t, W2t);

    // --- CSR build ---
    hipMemsetAsync(deg, 0, N_NODES * sizeof(int), stream);
    hist_dst<<<(E_EDGES + 255) / 256, blk, 0, stream>>>(dst, deg, E_EDGES);
    scan_local<<<NB_SCAN, blk, 0, stream>>>(deg, locpre, blockSum);
    scan_final<<<NB_SCAN, blk, 0, stream>>>(locpre, blockSum, rowptr, cursor);
    scatter_edges<<<(E_EDGES + 255) / 256, blk, 0, stream>>>(src, dst, cursor, ssrc, E_EDGES);

    // --- Layer 1: [N,128] @ [128,512] (fused Wl|Wr), 128x256 tiles ---
    gemm_mfma<float><<<dim3(gemm_gx, 2), blk, 0, stream>>>(x, W1t, xlr1, N_NODES, 128, 512);
    agg1<<<(N_NODES * 64 + 255) / 256, blk, 0, stream>>>(xlr1, rowptr, ssrc, att1, b1, hh);

    // --- Layer 2: [N,256] @ [256,256] (fused Wl|Wr), 128x256 tiles ---
    gemm_mfma<_Float16><<<dim3(gemm_gx, 1), blk, 0, stream>>>((const _Float16*)hh, W2t, xlr2, N_NODES, 256, 256);
    agg2<<<(N_NODES * 64 + 255) / 256, blk, 0, stream>>>(xlr2, rowptr, ssrc, att2, b2, out);
}

// Round 11
// 336.085 us; speedup vs baseline: 1.0668x; 1.0668x over previous
//
#include <hip/hip_runtime.h>
#include <hip/hip_bf16.h>
#include <hip/hip_fp16.h>
#include <math.h>

#define N_NODES 50000
#define E_EDGES 800000
#define NEG_SLOPE 0.2f
#define EPS 1e-16f
#define NB_SCAN ((N_NODES + 255) / 256)   // 196

typedef _Float16 f16x8 __attribute__((ext_vector_type(8)));
typedef _Float16 h2f   __attribute__((ext_vector_type(2)));
typedef float    f32x4 __attribute__((ext_vector_type(4)));

__device__ __forceinline__ float leaky(float v) {
    return v > 0.f ? v : NEG_SLOPE * v;
}

// fp32 dot-accumulate of an fp16 pair product: v_dot2_f32_f16 where available
__device__ __forceinline__ float dot2acc(h2f a, h2f b, float c) {
#if __has_builtin(__builtin_amdgcn_fdot2)
    return __builtin_amdgcn_fdot2(a, b, c, false);
#else
    return c + (float)a[0] * (float)b[0] + (float)a[1] * (float)b[1];
#endif
}

// packed leaky-relu: max(s, 0.2*s) elementwise (v_pk_mul + v_pk_max)
__device__ __forceinline__ h2f leaky2(h2f s) {
    h2f t = s * (_Float16)NEG_SLOPE;
    return __builtin_elementwise_max(s, t);
}

__device__ __forceinline__ h2f cvt_h2(float x, float y) {
    h2f r; r[0] = (_Float16)x; r[1] = (_Float16)y; return r;
}

// load 8 contiguous elements as f16x8, converting if input is fp32
__device__ __forceinline__ f16x8 load8(const float* p) {
    const float4 v0 = *(const float4*)p;
    const float4 v1 = *(const float4*)(p + 4);
    f16x8 r;
    r[0] = (_Float16)v0.x; r[1] = (_Float16)v0.y;
    r[2] = (_Float16)v0.z; r[3] = (_Float16)v0.w;
    r[4] = (_Float16)v1.x; r[5] = (_Float16)v1.y;
    r[6] = (_Float16)v1.z; r[7] = (_Float16)v1.w;
    return r;
}
__device__ __forceinline__ f16x8 load8(const _Float16* p) {
    return *(const f16x8*)p;
}

// ---------------------------------------------------------------------------
// MFMA GEMM (fp16 compute, fp32 accum): Y[N, M2] = X[N,K] @ Wt[M2,K]^T,
// fp16 output. X fp32 (converted during staging) or fp16, templated.
// 128x256 tile, BK=32, 4 waves (2x2 over 64x128 each), 4x8 MFMA tiles/wave.
// R9 orientation (measured best): acc = mfma(af, bf).
// ---------------------------------------------------------------------------
template <typename IT>
__global__ __launch_bounds__(256, 2)
void gemm_mfma(const IT* __restrict__ X, const __half* __restrict__ Wth,
               __half* __restrict__ Y, int Nrows, int K, int M2)
{
    const _Float16* Wt = (const _Float16*)Wth;
    __shared__ _Float16 As[128][40];
    __shared__ _Float16 Bs[256][40];
    const int tid  = threadIdx.x;
    const int row0 = blockIdx.x * 128;
    const int col0 = blockIdx.y * 256;
    const int lane = tid & 63;
    const int wv   = tid >> 6;
    const int wr   = (wv >> 1) * 64;
    const int wc   = (wv & 1) * 128;
    const int fm   = lane & 15;
    const int fk   = (lane >> 4) * 8;
    const int quad = lane >> 4;

    f32x4 acc[4][8] = {};

    for (int k0 = 0; k0 < K; k0 += 32) {
        #pragma unroll
        for (int p = 0; p < 2; ++p) {
            const int idx = tid + p * 256;
            const int r = idx >> 2;
            const int c = (idx & 3) * 8;
            const int gr = row0 + r;
            f16x8 v = {};
            if (gr < Nrows)
                v = load8(X + (size_t)gr * K + k0 + c);
            *(f16x8*)&As[r][c] = v;
        }
        #pragma unroll
        for (int p = 0; p < 4; ++p) {
            const int idx = tid + p * 256;
            const int r = idx >> 2;
            const int c = (idx & 3) * 8;
            *(f16x8*)&Bs[r][c] = *(const f16x8*)(Wt + (size_t)(col0 + r) * K + k0 + c);
        }
        __syncthreads();

        f16x8 bf[8];
        #pragma unroll
        for (int j = 0; j < 8; ++j)
            bf[j] = *(const f16x8*)&Bs[wc + j * 16 + fm][fk];
        #pragma unroll
        for (int i = 0; i < 4; ++i) {
            const f16x8 af = *(const f16x8*)&As[wr + i * 16 + fm][fk];
            #pragma unroll
            for (int j = 0; j < 8; ++j)
                acc[i][j] = __builtin_amdgcn_mfma_f32_16x16x32_f16(af, bf[j], acc[i][j], 0, 0, 0);
        }
        __syncthreads();
    }

    #pragma unroll
    for (int i = 0; i < 4; ++i) {
        #pragma unroll
        for (int j = 0; j < 8; ++j) {
            const int col = col0 + wc + j * 16 + fm;
            #pragma unroll
            for (int rg = 0; rg < 4; ++rg) {
                const int row = row0 + wr + i * 16 + quad * 4 + rg;
                if (row < Nrows)
                    Y[(size_t)row * M2 + col] = __float2half(acc[i][j][rg]);
            }
        }
    }
}

// ---------------------------------------------------------------------------
// Fused: weight-pair fp16 transpose convert (blocks 0..511) + dst histogram
// (remaining blocks). deg must be zeroed beforehand (same-stream memset).
// ---------------------------------------------------------------------------
#define CVT_BLOCKS 512   // (512*128 + 256*256) / 256
__global__ __launch_bounds__(256)
void cvt_and_hist(const float* __restrict__ Wl1, const float* __restrict__ Wr1,
                  const float* __restrict__ Wl2, const float* __restrict__ Wr2,
                  __half* __restrict__ W1t, __half* __restrict__ W2t,
                  const int* __restrict__ dst, int* __restrict__ deg)
{
    const int b = blockIdx.x;
    if (b < CVT_BLOCKS) {
        int id = b * 256 + threadIdx.x;
        if (id < 512 * 128) {
            const int n = id >> 7, k = id & 127;          // K=128, M=256
            const float* W = (n < 256) ? Wl1 : Wr1;
            const int nn = (n < 256) ? n : n - 256;
            W1t[id] = __float2half(W[(size_t)k * 256 + nn]);
        } else {
            id -= 512 * 128;
            const int n = id >> 8, k = id & 255;          // K=256, M=128
            const float* W = (n < 128) ? Wl2 : Wr2;
            const int nn = (n < 128) ? n : n - 128;
            W2t[id] = __float2half(W[(size_t)k * 128 + nn]);
        }
    } else {
        const int i = (b - CVT_BLOCKS) * 256 + threadIdx.x;
        if (i < E_EDGES) atomicAdd(&deg[dst[i]], 1);
    }
}

__global__ __launch_bounds__(256)
void scan_local(const int* __restrict__ deg, int* __restrict__ locpre,
                int* __restrict__ blockSum)
{
    const int i = blockIdx.x * 256 + threadIdx.x;
    const int lane = threadIdx.x & 63;
    const int wid = threadIdx.x >> 6;
    const int val = (i < N_NODES) ? deg[i] : 0;

    int v = val;
    #pragma unroll
    for (int off = 1; off < 64; off <<= 1) {
        int t = __shfl_up(v, off, 64);
        if (lane >= off) v += t;
    }
    __shared__ int ws[4];
    if (lane == 63) ws[wid] = v;
    __syncthreads();
    int woff = 0;
    for (int k = 0; k < wid; ++k) woff += ws[k];
    if (i < N_NODES) locpre[i] = woff + v - val;
    if (threadIdx.x == 255) blockSum[blockIdx.x] = woff + v;
}

__global__ __launch_bounds__(256)
void scan_final(const int* __restrict__ locpre, const int* __restrict__ blockSum,
                int* __restrict__ rowptr, int* __restrict__ cursor)
{
    const int b = blockIdx.x;
    const int t = threadIdx.x;
    int v = (t < b) ? blockSum[t] : 0;          // NB_SCAN(=196) < 256
    #pragma unroll
    for (int off = 32; off; off >>= 1) v += __shfl_xor(v, off, 64);
    __shared__ int ws[4];
    if ((t & 63) == 0) ws[t >> 6] = v;
    __syncthreads();
    const int offset = ws[0] + ws[1] + ws[2] + ws[3];

    const int i = b * 256 + t;
    if (i < N_NODES) {
        const int rp = locpre[i] + offset;
        rowptr[i] = rp;
        cursor[i] = rp;
    }
    if (b == 0 && t == 0) rowptr[N_NODES] = E_EDGES;
}

__global__ __launch_bounds__(256)
void scatter_edges(const int* __restrict__ src, const int* __restrict__ dst,
                   int* __restrict__ cursor, int* __restrict__ ssrc, int E)
{
    int i = blockIdx.x * blockDim.x + threadIdx.x;
    if (i < E) {
        int pos = atomicAdd(&cursor[dst[i]], 1);
        ssrc[pos] = src[i];
    }
}

// ---------------------------------------------------------------------------
// Layer-1 aggregation (H=4, C=64). One wave per dst node; lane owns 4 ch
// (head = lane>>4). 4-edge unroll; score math in PACKED fp16 (pk_add /
// pk_mul / pk_max) + v_dot2_f32_f16 accumulate; feature accumulate via
// mixed-precision fma (e * half -> float).
// ---------------------------------------------------------------------------
__global__ __launch_bounds__(256)
void agg1(const __half* __restrict__ xlr, const int* __restrict__ rowptr,
          const int* __restrict__ ssrc, const float* __restrict__ att,
          const float* __restrict__ b, __half* __restrict__ h)
{
    const int w = (blockIdx.x * blockDim.x + threadIdx.x) >> 6;
    if (w >= N_NODES) return;
    const int lane = threadIdx.x & 63;
    const int ch = lane * 4;

    const float4 atf = *(const float4*)(att + ch);
    const h2f at0 = cvt_h2(atf.x, atf.y);
    const h2f at1 = cvt_h2(atf.z, atf.w);
    const float4 bb = *(const float4*)(b + ch);
    union { uint2 u; h2f v[2]; } R;
    R.u = *(const uint2*)(xlr + (size_t)w * 512 + 256 + ch);
    const h2f r0 = R.v[0], r1 = R.v[1];

    float4 a = make_float4(0.f, 0.f, 0.f, 0.f);
    float den = 0.f;

    const int beg = rowptr[w], end = rowptr[w + 1];
    int i = beg;
    while (i + 4 <= end) {
        union { uint2 u; h2f v[2]; } U[4];
        #pragma unroll
        for (int j = 0; j < 4; ++j) {
            const int s = ssrc[i + j];
            U[j].u = *(const uint2*)(xlr + (size_t)s * 512 + ch);
        }
        float m[4];
        #pragma unroll
        for (int j = 0; j < 4; ++j) {
            m[j] = dot2acc(leaky2(U[j].v[0] + r0), at0, 0.f);
            m[j] = dot2acc(leaky2(U[j].v[1] + r1), at1, m[j]);
        }
        #pragma unroll
        for (int off = 1; off < 16; off <<= 1)
            #pragma unroll
            for (int j = 0; j < 4; ++j)
                m[j] += __shfl_xor(m[j], off, 64);
        #pragma unroll
        for (int j = 0; j < 4; ++j) {
            const float e = __expf(m[j]);
            a.x += e * (float)U[j].v[0][0];
            a.y += e * (float)U[j].v[0][1];
            a.z += e * (float)U[j].v[1][0];
            a.w += e * (float)U[j].v[1][1];
            den += e;
        }
        i += 4;
    }
    while (i < end) {
        const int s = ssrc[i];
        union { uint2 u; h2f v[2]; } U;
        U.u = *(const uint2*)(xlr + (size_t)s * 512 + ch);
        float m = dot2acc(leaky2(U.v[0] + r0), at0, 0.f);
        m = dot2acc(leaky2(U.v[1] + r1), at1, m);
        m += __shfl_xor(m, 1, 64);
        m += __shfl_xor(m, 2, 64);
        m += __shfl_xor(m, 4, 64);
        m += __shfl_xor(m, 8, 64);
        const float e = __expf(m);
        a.x += e * (float)U.v[0][0];
        a.y += e * (float)U.v[0][1];
        a.z += e * (float)U.v[1][0];
        a.w += e * (float)U.v[1][1];
        den += e;
        ++i;
    }

    const float inv = 1.f / (den + EPS);
    float v0 = a.x * inv + bb.x;
    float v1 = a.y * inv + bb.y;
    float v2 = a.z * inv + bb.z;
    float v3 = a.w * inv + bb.w;
    v0 = v0 > 0.f ? v0 : __expf(v0) - 1.f;
    v1 = v1 > 0.f ? v1 : __expf(v1) - 1.f;
    v2 = v2 > 0.f ? v2 : __expf(v2) - 1.f;
    v3 = v3 > 0.f ? v3 : __expf(v3) - 1.f;
    union { uint2 u; __half2 h2[2]; } O;
    O.h2[0] = __floats2half2_rn(v0, v1);
    O.h2[1] = __floats2half2_rn(v2, v3);
    *(uint2*)(h + (size_t)w * 256 + ch) = O.u;
}

// ---------------------------------------------------------------------------
// Layer-2 aggregation (H=1, C=128). Two 32-lane halves, 2-edge unroll per
// half; packed-fp16 score math as agg1.
// ---------------------------------------------------------------------------
__global__ __launch_bounds__(256)
void agg2(const __half* __restrict__ xlr, const int* __restrict__ rowptr,
          const int* __restrict__ ssrc, const float* __restrict__ att,
          const float* __restrict__ b, float* __restrict__ out)
{
    const int w = (blockIdx.x * blockDim.x + threadIdx.x) >> 6;
    if (w >= N_NODES) return;
    const int lane = threadIdx.x & 63;
    const int half = lane >> 5;
    const int ch = (lane & 31) * 4;

    const float4 atf = *(const float4*)(att + ch);
    const h2f at0 = cvt_h2(atf.x, atf.y);
    const h2f at1 = cvt_h2(atf.z, atf.w);
    const float4 bb = *(const float4*)(b + ch);
    union { uint2 u; h2f v[2]; } R;
    R.u = *(const uint2*)(xlr + (size_t)w * 256 + 128 + ch);
    const h2f r0 = R.v[0], r1 = R.v[1];

    float4 a = make_float4(0.f, 0.f, 0.f, 0.f);
    float den = 0.f;

    const int beg = rowptr[w], end = rowptr[w + 1];
    int i = beg + half;
    while (i + 2 < end) {
        union { uint2 u; h2f v[2]; } U[2];
        #pragma unroll
        for (int j = 0; j < 2; ++j) {
            const int s = ssrc[i + 2 * j];
            U[j].u = *(const uint2*)(xlr + (size_t)s * 256 + ch);
        }
        float m[2];
        #pragma unroll
        for (int j = 0; j < 2; ++j) {
            m[j] = dot2acc(leaky2(U[j].v[0] + r0), at0, 0.f);
            m[j] = dot2acc(leaky2(U[j].v[1] + r1), at1, m[j]);
        }
        #pragma unroll
        for (int off = 1; off < 32; off <<= 1)
            #pragma unroll
            for (int j = 0; j < 2; ++j)
                m[j] += __shfl_xor(m[j], off, 64);
        #pragma unroll
        for (int j = 0; j < 2; ++j) {
            const float e = __expf(m[j]);
            a.x += e * (float)U[j].v[0][0];
            a.y += e * (float)U[j].v[0][1];
            a.z += e * (float)U[j].v[1][0];
            a.w += e * (float)U[j].v[1][1];
            den += e;
        }
        i += 4;
    }
    if (i < end) {
        const int s = ssrc[i];
        union { uint2 u; h2f v[2]; } U;
        U.u = *(const uint2*)(xlr + (size_t)s * 256 + ch);
        float m = dot2acc(leaky2(U.v[0] + r0), at0, 0.f);
        m = dot2acc(leaky2(U.v[1] + r1), at1, m);
        #pragma unroll
        for (int off = 1; off < 32; off <<= 1)
            m += __shfl_xor(m, off, 64);
        const float e = __expf(m);
        a.x += e * (float)U.v[0][0];
        a.y += e * (float)U.v[0][1];
        a.z += e * (float)U.v[1][0];
        a.w += e * (float)U.v[1][1];
        den += e;
    }

    a.x += __shfl_xor(a.x, 32, 64);
    a.y += __shfl_xor(a.y, 32, 64);
    a.z += __shfl_xor(a.z, 32, 64);
    a.w += __shfl_xor(a.w, 32, 64);
    den += __shfl_xor(den, 32, 64);

    if (half == 0) {
        const float inv = 1.f / (den + EPS);
        float4 o;
        o.x = a.x * inv + bb.x;
        o.y = a.y * inv + bb.y;
        o.z = a.z * inv + bb.z;
        o.w = a.w * inv + bb.w;
        *(float4*)(out + (size_t)w * 128 + ch) = o;
    }
}

extern "C" void kernel_launch(void* const* d_in, const int* in_sizes, int n_in,
                              void* d_out, int out_size, void* d_ws, size_t ws_size,
                              hipStream_t stream)
{
    const float* x    = (const float*)d_in[0];
    const int*   ei   = (const int*)d_in[1];
    const float* Wl1  = (const float*)d_in[2];
    const float* Wr1  = (const float*)d_in[3];
    const float* att1 = (const float*)d_in[4];
    const float* b1   = (const float*)d_in[5];
    const float* Wl2  = (const float*)d_in[6];
    const float* Wr2  = (const float*)d_in[7];
    const float* att2 = (const float*)d_in[8];
    const float* b2   = (const float*)d_in[9];
    const int* src = ei;
    const int* dst = ei + E_EDGES;
    float* out = (float*)d_out;

    // Workspace layout (fp16 unless noted):
    //   xlr1 [N,512] = [xl1|xr1]   (51.2 MB)
    //   hh   [N,256]               (layer-1 ELU output)
    //   xlr2 [N,256] = [xl2|xr2]   (overlays xlr1 — dead after agg1)
    //   W1t  [512,128], W2t [256,256]
    //   ints: rowptr[N+1], cursor[N], deg[N], ssrc[E], locpre[N], blockSum[NB]
    __half* xlr1 = (__half*)d_ws;
    __half* hh   = xlr1 + (size_t)N_NODES * 512;
    __half* W1t  = hh + (size_t)N_NODES * 256;
    __half* W2t  = W1t + 512 * 128;
    int* rowptr   = (int*)(W2t + 256 * 256);
    int* cursor   = rowptr + (N_NODES + 1);
    int* deg      = cursor + N_NODES;
    int* ssrc     = deg + N_NODES;
    int* locpre   = ssrc + E_EDGES;
    int* blockSum = locpre + N_NODES;
    __half* xlr2 = xlr1;

    const dim3 blk(256);
    const int gemm_gx = (N_NODES + 127) / 128;   // 391
    const int hist_blocks = (E_EDGES + 255) / 256;

    // --- weight convert + dst histogram (fused, one launch) ---
    hipMemsetAsync(deg, 0, N_NODES * sizeof(int), stream);
    cvt_and_hist<<<CVT_BLOCKS + hist_blocks, blk, 0, stream>>>(
        Wl1, Wr1, Wl2, Wr2, W1t, W2t, dst, deg);
    scan_local<<<NB_SCAN, blk, 0, stream>>>(deg, locpre, blockSum);
    scan_final<<<NB_SCAN, blk, 0, stream>>>(locpre, blockSum, rowptr, cursor);
    scatter_edges<<<hist_blocks, blk, 0, stream>>>(src, dst, cursor, ssrc, E_EDGES);

    // --- Layer 1: [N,128] @ [128,512] (fused Wl|Wr), 128x256 tiles ---
    gemm_mfma<float><<<dim3(gemm_gx, 2), blk, 0, stream>>>(x, W1t, xlr1, N_NODES, 128, 512);
    agg1<<<(N_NODES * 64 + 255) / 256, blk, 0, stream>>>(xlr1, rowptr, ssrc, att1, b1, hh);

    // --- Layer 2: [N,256] @ [256,256] (fused Wl|Wr), 128x256 tiles ---
    gemm_mfma<_Float16><<<dim3(gemm_gx, 1), blk, 0, stream>>>((const _Float16*)hh, W2t, xlr2, N_NODES, 256, 256);
    agg2<<<(N_NODES * 64 + 255) / 256, blk, 0, stream>>>(xlr2, rowptr, ssrc, att2, b2, out);
}